// Round 15
// baseline (1101.231 us; speedup 1.0000x reference)
//
#include <hip/hip_runtime.h>

typedef __attribute__((ext_vector_type(8))) short bf16x8;
typedef __attribute__((ext_vector_type(4))) float f32x4;

#define L_DIM 24
#define B_DIM 32
#define S_DIM 512
#define H_DIM 1024
#define M_DIM 16384      // B*S
#define K_DIM 24576      // L*H
#define N_REAL 900
#define NP 1024          // padded N
#define BM 192           // m-tile (0.75x blocks -> ~55 panels -> ~220 actives)

#define W1T_TILES 6144   // 16 x 384 tiles of 64x64
#define SMALL_CHUNKS 164

// round-to-nearest-even fp32 -> bf16
__device__ __forceinline__ short f2bf(float f) {
  unsigned u = __builtin_bit_cast(unsigned, f);
  u += 0x7FFFu + ((u >> 16) & 1u);
  return (short)(u >> 16);
}

// ---- C1: per-batch flags + local prefix of unique nonzero starts (sorted input)
__global__ __launch_bounds__(512)
void compact1_kernel(const int* __restrict__ starts, int* __restrict__ upos,
                     int* __restrict__ counts) {
  __shared__ int sc[512];
  const int b = blockIdx.x, t = threadIdx.x;
  const int v = starts[b * 512 + t];
  const int prev = (t > 0) ? starts[b * 512 + t - 1] : -1;
  const int flag = (v != 0 && v != prev) ? 1 : 0;
  sc[t] = flag;
  __syncthreads();
#pragma unroll
  for (int off = 1; off < 512; off <<= 1) {
    const int x = (t >= off) ? sc[t - off] : 0;
    __syncthreads();
    sc[t] += x;
    __syncthreads();
  }
  upos[b * 512 + t] = flag ? (sc[t] - 1) : -1;
  if (t == 511) counts[b] = sc[511];
}

// ---- C2: scan counts -> offsets, Mc, Mc_pad (192-mult); pad idx tail with row 0
__global__ __launch_bounds__(256)
void compact2_kernel(const int* __restrict__ counts, int* __restrict__ offs,
                     int* __restrict__ meta, int* __restrict__ idx) {
  __shared__ int s0, s1;
  if (threadIdx.x == 0) {
    int acc = 0;
    for (int b = 0; b < 32; ++b) { offs[b] = acc; acc += counts[b]; }
    const int pad = ((acc + BM - 1) / BM) * BM;
    meta[0] = acc;                        // Mc
    meta[1] = pad;                        // Mc_pad (BM multiple)
    s0 = acc; s1 = pad;
  }
  __syncthreads();
  for (int j = s0 + threadIdx.x; j < s1; j += 256) idx[j] = 0;  // pad -> row 0
}

// ---- C3: scatter compact indices: idx[off_b + pos] = b*512 + value
__global__ __launch_bounds__(512)
void compact3_kernel(const int* __restrict__ starts, const int* __restrict__ upos,
                     const int* __restrict__ offs, int* __restrict__ idx) {
  const int b = blockIdx.x, t = threadIdx.x;
  const int p = upos[b * 512 + t];
  if (p >= 0) idx[offs[b] + p] = b * 512 + starts[b * 512 + t];
}

// =====================================================================
// P-fused: one kernel, three memory-bound work types co-resident so HBM
// stays saturated:
//   item < 6144              : one 64x64 W1->W1T transpose tile
//   item < 6144+Mc_pad       : one compacted-A row convert (fp32->bf16)
//   item < 6144+Mc_pad+164   : one prep_small chunk (W2T + b1p)
// =====================================================================
__global__ __launch_bounds__(256)
void prep_fused_kernel(const float* __restrict__ hs, const int* __restrict__ idx,
                       const int* __restrict__ meta,
                       const float* __restrict__ w1, const float* __restrict__ w2,
                       const float* __restrict__ b1,
                       unsigned short* __restrict__ a,
                       unsigned short* __restrict__ w1t,
                       float* __restrict__ w2t, float* __restrict__ b1p) {
  __shared__ unsigned short t[64][72];
  const int mcp = meta[1];
  const int total = W1T_TILES + mcp + SMALL_CHUNKS;
  const int tid = threadIdx.x;

  for (int item = blockIdx.x; item < total; item += gridDim.x) {
    if (item < W1T_TILES) {
      const int n0 = (item & 15) * 64;
      const int k0 = (item >> 4) * 64;
      {
        const int nl = tid & 63;
        const int n = n0 + nl;
#pragma unroll
        for (int p = 0; p < 16; ++p) {
          const int kl = p * 4 + (tid >> 6);
          float v = (n < N_REAL) ? w1[(size_t)(k0 + kl) * N_REAL + n] : 0.f;
          t[nl][kl] = (unsigned short)f2bf(v);
        }
      }
      __syncthreads();
      {
        const int kl = tid & 63;
#pragma unroll
        for (int p = 0; p < 16; ++p) {
          const int nl2 = p * 4 + (tid >> 6);
          const int n = n0 + nl2;
          const int slot = ((kl >> 3) ^ (n & 7)) & 7;
          w1t[(size_t)n * K_DIM + k0 + slot * 8 + (kl & 7)] = t[nl2][kl];
        }
      }
      __syncthreads();
    } else if (item < W1T_TILES + mcp) {
      const int j = item - W1T_TILES;
      const int m = idx[j];
      const int b = m >> 9, s = m & 511;
      const int j7 = j & 7;
      unsigned short* dstRow = a + (size_t)j * K_DIM;
#pragma unroll
      for (int i = 0; i < 12; ++i) {
        const int g = tid + i * 256;
        const int l = g >> 7;
        const int h = (g & 127) * 8;
        const float* src = hs + (((size_t)l * B_DIM + b) * S_DIM + s) * H_DIM + h;
        float4 f0 = *(const float4*)src;
        float4 f1 = *(const float4*)(src + 4);
        bf16x8 p;
        p[0] = f2bf(f0.x); p[1] = f2bf(f0.y); p[2] = f2bf(f0.z); p[3] = f2bf(f0.w);
        p[4] = f2bf(f1.x); p[5] = f2bf(f1.y); p[6] = f2bf(f1.z); p[7] = f2bf(f1.w);
        const int slot = (g & 7) ^ j7;
        *(bf16x8*)(dstRow + (g & ~7) * 8 + slot * 8) = p;
      }
    } else {
      const int i = (item - W1T_TILES - mcp) * 256 + tid;
      if (i < 40 * NP) {
        const int jj = i >> 10, k = i & (NP - 1);
        w2t[i] = (k < N_REAL) ? w2[(size_t)k * 40 + jj] : 0.f;
      }
      const int t2 = i - 40 * NP;
      if (t2 >= 0 && t2 < NP)
        b1p[t2] = (t2 < N_REAL) ? b1[t2] : 0.f;
    }
  }
}

// =====================================================================
// G1: h1 = relu(A @ W1T^T + b1). 192x256 tile, BK=64, TWO-phase tile
// (was 3): ph1 {read Aa+Ba+Bb, stage A(t+1)+Bb(t+1), 24 MFMA},
// ph2 {read Ab, stage Ba(t+2), 24 MFMA, vmcnt(2)}. 4 barriers/K-tile
// (was 6); identical staging queue: at each tile end vmcnt(2) drains
// exactly Ba(t+1),A(t+1),Bb(t+1) and keeps Ba(t+2) in flight. Every
// stage lands >=1 barrier after its buffer region's last read:
// A(t+1)->ABN (last read tile t-1 ph2-end), Bb(t+1)->BBN (t-1 ph1-end),
// Ba(t+2)->BB current (Ba read finished at t ph1-end barrier).
// =====================================================================
#define SBAR() do { __builtin_amdgcn_sched_barrier(0); __builtin_amdgcn_s_barrier(); __builtin_amdgcn_sched_barrier(0); } while (0)
#define WAIT_LGKM0() do { asm volatile("s_waitcnt lgkmcnt(0)" ::: "memory"); __builtin_amdgcn_sched_barrier(0); } while (0)
#define VMWAIT(N) do { asm volatile("s_waitcnt vmcnt(" #N ")" ::: "memory"); __builtin_amdgcn_sched_barrier(0); } while (0)

// stage full 192-row A tile (24 KiB): 3 x global_load_lds per thread
#define STAGE_A(DSTREG, TK) do {                                                       \
  _Pragma("unroll")                                                                    \
  for (int _i = 0; _i < 3; ++_i) {                                                     \
    const int _ch = wid * 3 + _i;                                                      \
    const int _row = _ch * 8 + (lane >> 3);                                            \
    __builtin_amdgcn_global_load_lds(                                                  \
      (const __attribute__((address_space(1))) void*)(a +                              \
          (size_t)(m0 + _row) * K_DIM + (TK) * 64 + (lane & 7) * 8),                   \
      (__attribute__((address_space(3))) void*)((DSTREG) + _ch * 1024),                \
      16, 0, 0);                                                                       \
  }                                                                                    \
} while (0)

// stage one 128-row half of B tile (16 KiB): 2 x global_load_lds per thread
#define STAGE_B(DSTREG, HALF, TK) do {                                                 \
  _Pragma("unroll")                                                                    \
  for (int _i = 0; _i < 2; ++_i) {                                                     \
    const int _ch = wid * 2 + _i;                                                      \
    const int _row = (HALF) * 128 + _ch * 8 + (lane >> 3);                             \
    __builtin_amdgcn_global_load_lds(                                                  \
      (const __attribute__((address_space(1))) void*)(w1t +                            \
          (size_t)(n0 + _row) * K_DIM + (TK) * 64 + (lane & 7) * 8),                   \
      (__attribute__((address_space(3))) void*)((DSTREG) + (HALF) * 16384 + _ch * 1024), \
      16, 0, 0);                                                                       \
  }                                                                                    \
} while (0)

// A fragments: half h = MIBASE/3; rows h*96 + wr*48 + {0,16,32} + r15, both kk
#define LDA3(AV, MIBASE, ABUF) do {                                                    \
  _Pragma("unroll")                                                                    \
  for (int _mi = 0; _mi < 3; ++_mi) {                                                  \
    _Pragma("unroll")                                                                  \
    for (int _kk = 0; _kk < 2; ++_kk) {                                                \
      const int _r = ((MIBASE) / 3) * 96 + wr * 48 + _mi * 16 + r15;                   \
      AV[_mi][_kk] = *(const bf16x8*)((ABUF) + _r * 128 + (((_kk)*4 + hi4) ^ (_r & 7)) * 16); \
    }                                                                                  \
  }                                                                                    \
} while (0)

// B fragments: half = NIBASE>>1; rows half*128 + wc*32 + {0,16} + r15, both kk
#define LDB2(BV, NIBASE, BBUF) do {                                                    \
  _Pragma("unroll")                                                                    \
  for (int _ni = 0; _ni < 2; ++_ni) {                                                  \
    _Pragma("unroll")                                                                  \
    for (int _kk = 0; _kk < 2; ++_kk) {                                                \
      const int _r = ((NIBASE) >> 1) * 128 + wc * 32 + _ni * 16 + r15;                 \
      BV[_ni][_kk] = *(const bf16x8*)((BBUF) + _r * 128 + (((_kk)*4 + hi4) ^ (_r & 7)) * 16); \
    }                                                                                  \
  }                                                                                    \
} while (0)

#define MFMA_Q(AV, BV, MIBASE, NIBASE) do {                                            \
  _Pragma("unroll")                                                                    \
  for (int _mi = 0; _mi < 3; ++_mi)                                                    \
    _Pragma("unroll")                                                                  \
    for (int _ni = 0; _ni < 2; ++_ni)                                                  \
      _Pragma("unroll")                                                                \
      for (int _kk = 0; _kk < 2; ++_kk)                                                \
        acc[(MIBASE) + _mi][(NIBASE) + _ni] = __builtin_amdgcn_mfma_f32_16x16x32_bf16( \
            AV[_mi][_kk], BV[_ni][_kk], acc[(MIBASE) + _mi][(NIBASE) + _ni], 0, 0, 0); \
} while (0)

// one K-tile = 2 phases. S1: stage A(t+1) into ABN + Bb(t+1) into BBN (ph1);
// S3: stage Ba(t+2) into BB current (ph2). WAITSTMT at ph2 end.
#define TILE_BODY(T, AB, BB, ABN, BBN, S1, S3, WAITSTMT) do {                          \
  /* ---- phase 1: Aa x (Ba, Bb) ---- */                                               \
  LDA3(av, 0, (AB));                                                                   \
  LDB2(bv0, 0, (BB));                                                                  \
  LDB2(bv1, 2, (BB));                                                                  \
  if (S1) { STAGE_A((ABN), (T) + 1); STAGE_B((BBN), 1, (T) + 1); }                     \
  SBAR();                                                                              \
  WAIT_LGKM0();                                                                        \
  __builtin_amdgcn_s_setprio(1);                                                       \
  MFMA_Q(av, bv0, 0, 0);                                                               \
  MFMA_Q(av, bv1, 0, 2);                                                               \
  __builtin_amdgcn_s_setprio(0);                                                       \
  SBAR();                                                                              \
  /* ---- phase 2: Ab x (Bb, Ba) ---- */                                               \
  LDA3(av, 3, (AB));                                                                   \
  if (S3) STAGE_B((BB), 0, (T) + 2);                                                   \
  SBAR();                                                                              \
  WAIT_LGKM0();                                                                        \
  __builtin_amdgcn_s_setprio(1);                                                       \
  MFMA_Q(av, bv1, 3, 2);                                                               \
  MFMA_Q(av, bv0, 3, 0);                                                               \
  __builtin_amdgcn_s_setprio(0);                                                       \
  WAITSTMT;                                                                            \
  SBAR();                                                                              \
} while (0)

__global__ __launch_bounds__(512, 2)
void gemm1_192_kernel(const unsigned short* __restrict__ a,
                      const unsigned short* __restrict__ w1t,
                      const float* __restrict__ b1p,
                      const int* __restrict__ meta,
                      float* __restrict__ h1) {
  const int n_panels = meta[1] / BM;

  // XCD mapping: panel mb's 4 n-blocks share XCD c = mb&7
  const int hw = blockIdx.x;
  const int c = hw & 7;
  const int r = hw >> 3;              // 0..43
  const int mb = (r >> 2) * 8 + c;
  if (mb >= n_panels) return;
  const int nb = r & 3;
  const int m0 = mb * BM;
  const int n0 = nb * 256;

  extern __shared__ char L[];   // 112 KiB: A0(24K)|A1(24K)|B0(32K)|B1(32K)
  char* const Ab0 = L;
  char* const Ab1 = L + 24576;
  char* const Bb0 = L + 49152;
  char* const Bb1 = L + 49152 + 32768;

  const int tid = threadIdx.x;
  const int lane = tid & 63;
  const int wid = tid >> 6;          // 0..7
  const int wr = wid >> 2;           // 0..1 (48-row band within each 96-half)
  const int wc = wid & 3;            // 0..3 (32-col band within each 128-half)
  const int r15 = lane & 15;
  const int hi4 = lane >> 4;         // 0..3

  f32x4 acc[6][4] = {};
  bf16x8 av[3][2], bv0[2][2], bv1[2][2];

  // prologue, steady queue order: [Ba(0)2, A(0)3, Bb(0)2, Ba(1)2]
  STAGE_B(Bb0, 0, 0);
  STAGE_A(Ab0, 0);
  STAGE_B(Bb0, 1, 0);
  STAGE_B(Bb1, 0, 1);
  VMWAIT(2);      // land Ba(0), A(0), Bb(0); keep Ba(1) in flight
  SBAR();

  for (int kt = 0; kt < 191; ++kt) {
    const int t = 2 * kt;
    TILE_BODY(t,     Ab0, Bb0, Ab1, Bb1, 1, 1, VMWAIT(2));
    TILE_BODY(t + 1, Ab1, Bb1, Ab0, Bb0, 1, 1, VMWAIT(2));
  }
  // tail: 382 stages A(383)+Bb(383), full drain; 383 computes only
  TILE_BODY(382, Ab0, Bb0, Ab1, Bb1, 1, 0, VMWAIT(0));
  TILE_BODY(383, Ab1, Bb1, Ab0, Bb0, 0, 0, (void)0);

  // epilogue: relu(acc + b1); C/D: col = lane&15, row = (lane>>4)*4 + rr
#pragma unroll
  for (int mi = 0; mi < 6; ++mi) {
#pragma unroll
    for (int ni = 0; ni < 4; ++ni) {
      const int n = n0 + (ni >> 1) * 128 + wc * 32 + (ni & 1) * 16 + r15;
      const float bias = b1p[n];
#pragma unroll
      for (int rr = 0; rr < 4; ++rr) {
        const int m = m0 + (mi / 3) * 96 + wr * 48 + (mi % 3) * 16 + hi4 * 4 + rr;
        const float v = acc[mi][ni][rr] + bias;
        h1[(size_t)m * NP + n] = v > 0.f ? v : 0.f;
      }
    }
  }
}

// ---- K2: logits = sigmoid(relu(h1 @ W2 + b2) @ W3 + b3), one wave per
//          COMPACT row j; writes logits at the original position idx[j].
__global__ __launch_bounds__(256)
void layer23_kernel(const float* __restrict__ h1, const float* __restrict__ w2t,
                    const float* __restrict__ b2, const float* __restrict__ w3,
                    const float* __restrict__ b3, const int* __restrict__ idx,
                    const int* __restrict__ meta, float* __restrict__ logits) {
  const int j = (blockIdx.x * 256 + threadIdx.x) >> 6;
  if (j >= meta[0]) return;
  const int lane = threadIdx.x & 63;
  const float* hrow = h1 + (size_t)j * NP;
  float acc = 0.f;
  if (lane < 40) {
    const float* wrow = w2t + lane * NP;
    for (int k = 0; k < NP; k += 8) {
      float4 h0 = *(const float4*)(hrow + k);
      float4 h4 = *(const float4*)(hrow + k + 4);
      float4 w0 = *(const float4*)(wrow + k);
      float4 w4 = *(const float4*)(wrow + k + 4);
      acc += h0.x * w0.x + h0.y * w0.y + h0.z * w0.z + h0.w * w0.w;
      acc += h4.x * w4.x + h4.y * w4.y + h4.z * w4.z + h4.w * w4.w;
    }
    acc += b2[lane];
    acc = acc > 0.f ? acc : 0.f;
    acc *= w3[lane];
  }
#pragma unroll
  for (int off = 32; off > 0; off >>= 1)
    acc += __shfl_down(acc, off);
  if (lane == 0)
    logits[idx[j]] = 1.f / (1.f + expf(-(acc + b3[0])));
}

// ---- K3: ragged gather
__global__ __launch_bounds__(256)
void gather_kernel(const int* __restrict__ starts, const float* __restrict__ logits,
                   float* __restrict__ out) {
  const int i = blockIdx.x * 256 + threadIdx.x;
  if (i >= M_DIM) return;
  const int st = starts[i];
  int idx = st;
  if (idx < 0) idx = 0;
  if (idx > S_DIM - 1) idx = S_DIM - 1;
  out[i] = (st != 0) ? logits[((i >> 9) << 9) + idx] : 0.f;
}

extern "C" void kernel_launch(void* const* d_in, const int* in_sizes, int n_in,
                              void* d_out, int out_size, void* d_ws, size_t ws_size,
                              hipStream_t stream) {
  const float* hs = (const float*)d_in[0];
  const float* W1 = (const float*)d_in[1];
  const float* b1 = (const float*)d_in[2];
  const float* W2 = (const float*)d_in[3];
  const float* b2 = (const float*)d_in[4];
  const float* W3 = (const float*)d_in[5];
  const float* b3 = (const float*)d_in[6];
  const int* starts = (const int*)d_in[7];
  float* out = (float*)d_out;
  char* ws = (char*)d_ws;

  const size_t A_BYTES   = (size_t)(M_DIM + 256) * K_DIM * 2;  // slack for 192-pad
  const size_t W1T_BYTES = (size_t)NP * K_DIM * 2;             //    50,331,648
  const size_t H1_BYTES  = (size_t)(M_DIM + 256) * NP * 4;
  const size_t W2T_BYTES = 40 * NP * 4;
  const size_t B1P_BYTES = NP * 4;
  const size_t LG_BYTES  = M_DIM * 4;

  unsigned short* a    = (unsigned short*)ws;
  unsigned short* w1t  = (unsigned short*)(ws + A_BYTES);
  char* h1c            = ws + A_BYTES + W1T_BYTES;
  float* h1            = (float*)h1c;
  float* w2t           = (float*)(ws + A_BYTES + W1T_BYTES + H1_BYTES);
  float* b1p           = (float*)(ws + A_BYTES + W1T_BYTES + H1_BYTES + W2T_BYTES);
  float* logits        = (float*)(ws + A_BYTES + W1T_BYTES + H1_BYTES + W2T_BYTES + B1P_BYTES);
  int* idx             = (int*)(ws + A_BYTES + W1T_BYTES + H1_BYTES + W2T_BYTES + B1P_BYTES + LG_BYTES);
  int* meta            = (int*)(ws + A_BYTES + W1T_BYTES + H1_BYTES + W2T_BYTES + B1P_BYTES + LG_BYTES + 66560);
  // transient compaction scratch lives inside h1 (h1 is written only later)
  int* upos            = (int*)h1c;                 // 64 KiB
  int* counts          = (int*)(h1c + 65536);       // 128 B
  int* offs            = (int*)(h1c + 65536 + 128); // 128 B

  hipFuncSetAttribute((const void*)gemm1_192_kernel,
                      hipFuncAttributeMaxDynamicSharedMemorySize, 114688);

  compact1_kernel<<<32, 512, 0, stream>>>(starts, upos, counts);
  compact2_kernel<<<1, 256, 0, stream>>>(counts, offs, meta, idx);
  compact3_kernel<<<32, 512, 0, stream>>>(starts, upos, offs, idx);
  prep_fused_kernel<<<4096, 256, 0, stream>>>(hs, idx, meta, W1, W2, b1,
                                              a, w1t, w2t, b1p);
  gemm1_192_kernel<<<352, 512, 114688, stream>>>(a, w1t, b1p, meta, h1);
  layer23_kernel<<<4096, 256, 0, stream>>>(h1, w2t, b2, W3, b3, idx, meta, logits);
  gather_kernel<<<64, 256, 0, stream>>>(starts, logits, out);
}

// Round 16
// 1039.007 us; speedup vs baseline: 1.0599x; 1.0599x over previous
//
#include <hip/hip_runtime.h>

typedef __attribute__((ext_vector_type(8))) short bf16x8;
typedef __attribute__((ext_vector_type(4))) float f32x4;

#define L_DIM 24
#define B_DIM 32
#define S_DIM 512
#define H_DIM 1024
#define M_DIM 16384      // B*S
#define K_DIM 24576      // L*H
#define N_REAL 900
#define NP 1024          // padded N
#define BM 192           // m-tile (0.75x blocks -> ~55 panels -> ~220 actives)

#define W1T_TILES 6144   // 16 x 384 tiles of 64x64
#define SMALL_CHUNKS 164

// round-to-nearest-even fp32 -> bf16
__device__ __forceinline__ short f2bf(float f) {
  unsigned u = __builtin_bit_cast(unsigned, f);
  u += 0x7FFFu + ((u >> 16) & 1u);
  return (short)(u >> 16);
}
__device__ __forceinline__ float bflo(unsigned u) { return __builtin_bit_cast(float, u << 16); }
__device__ __forceinline__ float bfhi(unsigned u) { return __builtin_bit_cast(float, u & 0xffff0000u); }

// ---- C1: per-batch flags + local prefix of unique nonzero starts (sorted input)
__global__ __launch_bounds__(512)
void compact1_kernel(const int* __restrict__ starts, int* __restrict__ upos,
                     int* __restrict__ counts) {
  __shared__ int sc[512];
  const int b = blockIdx.x, t = threadIdx.x;
  const int v = starts[b * 512 + t];
  const int prev = (t > 0) ? starts[b * 512 + t - 1] : -1;
  const int flag = (v != 0 && v != prev) ? 1 : 0;
  sc[t] = flag;
  __syncthreads();
#pragma unroll
  for (int off = 1; off < 512; off <<= 1) {
    const int x = (t >= off) ? sc[t - off] : 0;
    __syncthreads();
    sc[t] += x;
    __syncthreads();
  }
  upos[b * 512 + t] = flag ? (sc[t] - 1) : -1;
  if (t == 511) counts[b] = sc[511];
}

// ---- C2: scan counts -> offsets, Mc, Mc_pad (192-mult); pad idx tail with row 0
__global__ __launch_bounds__(256)
void compact2_kernel(const int* __restrict__ counts, int* __restrict__ offs,
                     int* __restrict__ meta, int* __restrict__ idx) {
  __shared__ int s0, s1;
  if (threadIdx.x == 0) {
    int acc = 0;
    for (int b = 0; b < 32; ++b) { offs[b] = acc; acc += counts[b]; }
    const int pad = ((acc + BM - 1) / BM) * BM;
    meta[0] = acc;                        // Mc
    meta[1] = pad;                        // Mc_pad (BM multiple)
    s0 = acc; s1 = pad;
  }
  __syncthreads();
  for (int j = s0 + threadIdx.x; j < s1; j += 256) idx[j] = 0;  // pad -> row 0
}

// ---- C3: scatter compact indices: idx[off_b + pos] = b*512 + value
__global__ __launch_bounds__(512)
void compact3_kernel(const int* __restrict__ starts, const int* __restrict__ upos,
                     const int* __restrict__ offs, int* __restrict__ idx) {
  const int b = blockIdx.x, t = threadIdx.x;
  const int p = upos[b * 512 + t];
  if (p >= 0) idx[offs[b] + p] = b * 512 + starts[b * 512 + t];
}

// =====================================================================
// P-fused: one kernel, three memory-bound work types co-resident so HBM
// stays saturated:
//   item < 6144              : one 64x64 W1->W1T transpose tile
//   item < 6144+Mc_pad       : one compacted-A row convert (fp32->bf16)
//   item < 6144+Mc_pad+164   : one prep_small chunk (W2T + b1p)
// =====================================================================
__global__ __launch_bounds__(256)
void prep_fused_kernel(const float* __restrict__ hs, const int* __restrict__ idx,
                       const int* __restrict__ meta,
                       const float* __restrict__ w1, const float* __restrict__ w2,
                       const float* __restrict__ b1,
                       unsigned short* __restrict__ a,
                       unsigned short* __restrict__ w1t,
                       float* __restrict__ w2t, float* __restrict__ b1p) {
  __shared__ unsigned short t[64][72];
  const int mcp = meta[1];
  const int total = W1T_TILES + mcp + SMALL_CHUNKS;
  const int tid = threadIdx.x;

  for (int item = blockIdx.x; item < total; item += gridDim.x) {
    if (item < W1T_TILES) {
      const int n0 = (item & 15) * 64;
      const int k0 = (item >> 4) * 64;
      {
        const int nl = tid & 63;
        const int n = n0 + nl;
#pragma unroll
        for (int p = 0; p < 16; ++p) {
          const int kl = p * 4 + (tid >> 6);
          float v = (n < N_REAL) ? w1[(size_t)(k0 + kl) * N_REAL + n] : 0.f;
          t[nl][kl] = (unsigned short)f2bf(v);
        }
      }
      __syncthreads();
      {
        const int kl = tid & 63;
#pragma unroll
        for (int p = 0; p < 16; ++p) {
          const int nl2 = p * 4 + (tid >> 6);
          const int n = n0 + nl2;
          const int slot = ((kl >> 3) ^ (n & 7)) & 7;
          w1t[(size_t)n * K_DIM + k0 + slot * 8 + (kl & 7)] = t[nl2][kl];
        }
      }
      __syncthreads();
    } else if (item < W1T_TILES + mcp) {
      const int j = item - W1T_TILES;
      const int m = idx[j];
      const int b = m >> 9, s = m & 511;
      const int j7 = j & 7;
      unsigned short* dstRow = a + (size_t)j * K_DIM;
#pragma unroll
      for (int i = 0; i < 12; ++i) {
        const int g = tid + i * 256;
        const int l = g >> 7;
        const int h = (g & 127) * 8;
        const float* src = hs + (((size_t)l * B_DIM + b) * S_DIM + s) * H_DIM + h;
        float4 f0 = *(const float4*)src;
        float4 f1 = *(const float4*)(src + 4);
        bf16x8 p;
        p[0] = f2bf(f0.x); p[1] = f2bf(f0.y); p[2] = f2bf(f0.z); p[3] = f2bf(f0.w);
        p[4] = f2bf(f1.x); p[5] = f2bf(f1.y); p[6] = f2bf(f1.z); p[7] = f2bf(f1.w);
        const int slot = (g & 7) ^ j7;
        *(bf16x8*)(dstRow + (g & ~7) * 8 + slot * 8) = p;
      }
    } else {
      const int i = (item - W1T_TILES - mcp) * 256 + tid;
      if (i < 40 * NP) {
        const int jj = i >> 10, k = i & (NP - 1);
        w2t[i] = (k < N_REAL) ? w2[(size_t)k * 40 + jj] : 0.f;
      }
      const int t2 = i - 40 * NP;
      if (t2 >= 0 && t2 < NP)
        b1p[t2] = (t2 < N_REAL) ? b1[t2] : 0.f;
    }
  }
}

// =====================================================================
// G1: h1(bf16) = relu(A @ W1T^T + b1). 192x256 tile, BK=64, 3-phase
// cadence (R13/R14-proven). ~55 panels x 4 n-blocks = ~220 actives
// (86% CU fill, one round), full-K per block, panel-per-XCD mapping.
// Per tile: ph1 {read Aa+Ba, stage A(t+1)}, ph2 {read Bb, stage Bb(t+1)},
// ph3 {read Ab, stage Ba(t+2), 24 MFMA, vmcnt(2)}.
// =====================================================================
#define SBAR() do { __builtin_amdgcn_sched_barrier(0); __builtin_amdgcn_s_barrier(); __builtin_amdgcn_sched_barrier(0); } while (0)
#define WAIT_LGKM0() do { asm volatile("s_waitcnt lgkmcnt(0)" ::: "memory"); __builtin_amdgcn_sched_barrier(0); } while (0)
#define VMWAIT(N) do { asm volatile("s_waitcnt vmcnt(" #N ")" ::: "memory"); __builtin_amdgcn_sched_barrier(0); } while (0)

// stage full 192-row A tile (24 KiB): 3 x global_load_lds per thread
#define STAGE_A(DSTREG, TK) do {                                                       \
  _Pragma("unroll")                                                                    \
  for (int _i = 0; _i < 3; ++_i) {                                                     \
    const int _ch = wid * 3 + _i;                                                      \
    const int _row = _ch * 8 + (lane >> 3);                                            \
    __builtin_amdgcn_global_load_lds(                                                  \
      (const __attribute__((address_space(1))) void*)(a +                              \
          (size_t)(m0 + _row) * K_DIM + (TK) * 64 + (lane & 7) * 8),                   \
      (__attribute__((address_space(3))) void*)((DSTREG) + _ch * 1024),                \
      16, 0, 0);                                                                       \
  }                                                                                    \
} while (0)

// stage one 128-row half of B tile (16 KiB): 2 x global_load_lds per thread
#define STAGE_B(DSTREG, HALF, TK) do {                                                 \
  _Pragma("unroll")                                                                    \
  for (int _i = 0; _i < 2; ++_i) {                                                     \
    const int _ch = wid * 2 + _i;                                                      \
    const int _row = (HALF) * 128 + _ch * 8 + (lane >> 3);                             \
    __builtin_amdgcn_global_load_lds(                                                  \
      (const __attribute__((address_space(1))) void*)(w1t +                            \
          (size_t)(n0 + _row) * K_DIM + (TK) * 64 + (lane & 7) * 8),                   \
      (__attribute__((address_space(3))) void*)((DSTREG) + (HALF) * 16384 + _ch * 1024), \
      16, 0, 0);                                                                       \
  }                                                                                    \
} while (0)

// A fragments: half h = MIBASE/3; rows h*96 + wr*48 + {0,16,32} + r15, both kk
#define LDA3(AV, MIBASE, ABUF) do {                                                    \
  _Pragma("unroll")                                                                    \
  for (int _mi = 0; _mi < 3; ++_mi) {                                                  \
    _Pragma("unroll")                                                                  \
    for (int _kk = 0; _kk < 2; ++_kk) {                                                \
      const int _r = ((MIBASE) / 3) * 96 + wr * 48 + _mi * 16 + r15;                   \
      AV[_mi][_kk] = *(const bf16x8*)((ABUF) + _r * 128 + (((_kk)*4 + hi4) ^ (_r & 7)) * 16); \
    }                                                                                  \
  }                                                                                    \
} while (0)

// B fragments: half = NIBASE>>1; rows half*128 + wc*32 + {0,16} + r15, both kk
#define LDB2(BV, NIBASE, BBUF) do {                                                    \
  _Pragma("unroll")                                                                    \
  for (int _ni = 0; _ni < 2; ++_ni) {                                                  \
    _Pragma("unroll")                                                                  \
    for (int _kk = 0; _kk < 2; ++_kk) {                                                \
      const int _r = ((NIBASE) >> 1) * 128 + wc * 32 + _ni * 16 + r15;                 \
      BV[_ni][_kk] = *(const bf16x8*)((BBUF) + _r * 128 + (((_kk)*4 + hi4) ^ (_r & 7)) * 16); \
    }                                                                                  \
  }                                                                                    \
} while (0)

#define MFMA_Q(AV, BV, MIBASE, NIBASE) do {                                            \
  _Pragma("unroll")                                                                    \
  for (int _mi = 0; _mi < 3; ++_mi)                                                    \
    _Pragma("unroll")                                                                  \
    for (int _ni = 0; _ni < 2; ++_ni)                                                  \
      _Pragma("unroll")                                                                \
      for (int _kk = 0; _kk < 2; ++_kk)                                                \
        acc[(MIBASE) + _mi][(NIBASE) + _ni] = __builtin_amdgcn_mfma_f32_16x16x32_bf16( \
            AV[_mi][_kk], BV[_ni][_kk], acc[(MIBASE) + _mi][(NIBASE) + _ni], 0, 0, 0); \
} while (0)

// one K-tile = 3 phases. S1: stage A(t+1) full into ABN; S2: Bb(t+1) into
// BBN; S3: Ba(t+2) into BB (current; half a last read at ph1).
#define TILE_BODY(T, AB, BB, ABN, BBN, S1, S2, S3, WAITSTMT) do {                      \
  /* ---- phase 1: Aa x Ba ---- */                                                     \
  LDA3(av, 0, (AB));                                                                   \
  LDB2(bv0, 0, (BB));                                                                  \
  if (S1) STAGE_A((ABN), (T) + 1);                                                     \
  SBAR();                                                                              \
  WAIT_LGKM0();                                                                        \
  __builtin_amdgcn_s_setprio(1);                                                       \
  MFMA_Q(av, bv0, 0, 0);                                                               \
  __builtin_amdgcn_s_setprio(0);                                                       \
  SBAR();                                                                              \
  /* ---- phase 2: Aa x Bb ---- */                                                     \
  LDB2(bv1, 2, (BB));                                                                  \
  if (S2) STAGE_B((BBN), 1, (T) + 1);                                                  \
  SBAR();                                                                              \
  WAIT_LGKM0();                                                                        \
  __builtin_amdgcn_s_setprio(1);                                                       \
  MFMA_Q(av, bv1, 0, 2);                                                               \
  __builtin_amdgcn_s_setprio(0);                                                       \
  SBAR();                                                                              \
  /* ---- phase 3: Ab x (Bb, Ba) ---- */                                               \
  LDA3(av, 3, (AB));                                                                   \
  if (S3) STAGE_B((BB), 0, (T) + 2);                                                   \
  SBAR();                                                                              \
  WAIT_LGKM0();                                                                        \
  __builtin_amdgcn_s_setprio(1);                                                       \
  MFMA_Q(av, bv1, 3, 2);                                                               \
  MFMA_Q(av, bv0, 3, 0);                                                               \
  __builtin_amdgcn_s_setprio(0);                                                       \
  WAITSTMT;                                                                            \
  SBAR();                                                                              \
} while (0)

__global__ __launch_bounds__(512, 2)
void gemm1_192_kernel(const unsigned short* __restrict__ a,
                      const unsigned short* __restrict__ w1t,
                      const float* __restrict__ b1p,
                      const int* __restrict__ meta,
                      unsigned short* __restrict__ h1) {
  const int n_panels = meta[1] / BM;

  // XCD mapping: panel mb's 4 n-blocks share XCD c = mb&7
  const int hw = blockIdx.x;
  const int c = hw & 7;
  const int r = hw >> 3;              // 0..43
  const int mb = (r >> 2) * 8 + c;
  if (mb >= n_panels) return;
  const int nb = r & 3;
  const int m0 = mb * BM;
  const int n0 = nb * 256;

  extern __shared__ char L[];   // 112 KiB: A0(24K)|A1(24K)|B0(32K)|B1(32K)
  char* const Ab0 = L;
  char* const Ab1 = L + 24576;
  char* const Bb0 = L + 49152;
  char* const Bb1 = L + 49152 + 32768;

  const int tid = threadIdx.x;
  const int lane = tid & 63;
  const int wid = tid >> 6;          // 0..7
  const int wr = wid >> 2;           // 0..1 (48-row band within each 96-half)
  const int wc = wid & 3;            // 0..3 (32-col band within each 128-half)
  const int r15 = lane & 15;
  const int hi4 = lane >> 4;         // 0..3

  f32x4 acc[6][4] = {};
  bf16x8 av[3][2], bv0[2][2], bv1[2][2];

  // prologue, steady queue order: [Ba(0)2, A(0)3, Bb(0)2, Ba(1)2]
  STAGE_B(Bb0, 0, 0);
  STAGE_A(Ab0, 0);
  STAGE_B(Bb0, 1, 0);
  STAGE_B(Bb1, 0, 1);
  VMWAIT(2);      // land Ba(0), A(0), Bb(0); keep Ba(1) in flight
  SBAR();

  for (int kt = 0; kt < 191; ++kt) {
    const int t = 2 * kt;
    TILE_BODY(t,     Ab0, Bb0, Ab1, Bb1, 1, 1, 1, VMWAIT(2));
    TILE_BODY(t + 1, Ab1, Bb1, Ab0, Bb0, 1, 1, 1, VMWAIT(2));
  }
  // tail: 382 stages A(383)+Bb(383), full drain; 383 computes only
  TILE_BODY(382, Ab0, Bb0, Ab1, Bb1, 1, 1, 0, VMWAIT(0));
  TILE_BODY(383, Ab1, Bb1, Ab0, Bb0, 0, 0, 0, (void)0);

  // epilogue: relu(acc + b1) -> bf16; C/D: col = lane&15, row = (lane>>4)*4 + rr
#pragma unroll
  for (int mi = 0; mi < 6; ++mi) {
#pragma unroll
    for (int ni = 0; ni < 4; ++ni) {
      const int n = n0 + (ni >> 1) * 128 + wc * 32 + (ni & 1) * 16 + r15;
      const float bias = b1p[n];
#pragma unroll
      for (int rr = 0; rr < 4; ++rr) {
        const int m = m0 + (mi / 3) * 96 + wr * 48 + (mi % 3) * 16 + hi4 * 4 + rr;
        const float v = acc[mi][ni][rr] + bias;
        h1[(size_t)m * NP + n] = (unsigned short)f2bf(v > 0.f ? v : 0.f);
      }
    }
  }
}

// ---- K2: logits = sigmoid(relu(h1 @ W2 + b2) @ W3 + b3), one wave per
//          COMPACT row j (h1 in bf16); writes at original position idx[j].
__global__ __launch_bounds__(256)
void layer23_kernel(const unsigned short* __restrict__ h1, const float* __restrict__ w2t,
                    const float* __restrict__ b2, const float* __restrict__ w3,
                    const float* __restrict__ b3, const int* __restrict__ idx,
                    const int* __restrict__ meta, float* __restrict__ logits) {
  const int j = (blockIdx.x * 256 + threadIdx.x) >> 6;
  if (j >= meta[0]) return;
  const int lane = threadIdx.x & 63;
  const unsigned short* hrow = h1 + (size_t)j * NP;
  float acc = 0.f;
  if (lane < 40) {
    const float* wrow = w2t + lane * NP;
    for (int k = 0; k < NP; k += 8) {
      uint4 q = *(const uint4*)(hrow + k);
      float4 w0 = *(const float4*)(wrow + k);
      float4 w4 = *(const float4*)(wrow + k + 4);
      acc += bflo(q.x) * w0.x + bfhi(q.x) * w0.y;
      acc += bflo(q.y) * w0.z + bfhi(q.y) * w0.w;
      acc += bflo(q.z) * w4.x + bfhi(q.z) * w4.y;
      acc += bflo(q.w) * w4.z + bfhi(q.w) * w4.w;
    }
    acc += b2[lane];
    acc = acc > 0.f ? acc : 0.f;
    acc *= w3[lane];
  }
#pragma unroll
  for (int off = 32; off > 0; off >>= 1)
    acc += __shfl_down(acc, off);
  if (lane == 0)
    logits[idx[j]] = 1.f / (1.f + expf(-(acc + b3[0])));
}

// ---- K3: ragged gather
__global__ __launch_bounds__(256)
void gather_kernel(const int* __restrict__ starts, const float* __restrict__ logits,
                   float* __restrict__ out) {
  const int i = blockIdx.x * 256 + threadIdx.x;
  if (i >= M_DIM) return;
  const int st = starts[i];
  int idx = st;
  if (idx < 0) idx = 0;
  if (idx > S_DIM - 1) idx = S_DIM - 1;
  out[i] = (st != 0) ? logits[((i >> 9) << 9) + idx] : 0.f;
}

extern "C" void kernel_launch(void* const* d_in, const int* in_sizes, int n_in,
                              void* d_out, int out_size, void* d_ws, size_t ws_size,
                              hipStream_t stream) {
  const float* hs = (const float*)d_in[0];
  const float* W1 = (const float*)d_in[1];
  const float* b1 = (const float*)d_in[2];
  const float* W2 = (const float*)d_in[3];
  const float* b2 = (const float*)d_in[4];
  const float* W3 = (const float*)d_in[5];
  const float* b3 = (const float*)d_in[6];
  const int* starts = (const int*)d_in[7];
  float* out = (float*)d_out;
  char* ws = (char*)d_ws;

  const size_t A_BYTES   = (size_t)(M_DIM + 256) * K_DIM * 2;  // slack for 192-pad
  const size_t W1T_BYTES = (size_t)NP * K_DIM * 2;             //    50,331,648
  const size_t H1_BYTES  = (size_t)(M_DIM + 256) * NP * 2;     // bf16 h1
  const size_t W2T_BYTES = 40 * NP * 4;
  const size_t B1P_BYTES = NP * 4;
  const size_t LG_BYTES  = M_DIM * 4;

  unsigned short* a    = (unsigned short*)ws;
  unsigned short* w1t  = (unsigned short*)(ws + A_BYTES);
  char* h1c            = ws + A_BYTES + W1T_BYTES;
  unsigned short* h1   = (unsigned short*)h1c;
  float* w2t           = (float*)(ws + A_BYTES + W1T_BYTES + H1_BYTES);
  float* b1p           = (float*)(ws + A_BYTES + W1T_BYTES + H1_BYTES + W2T_BYTES);
  float* logits        = (float*)(ws + A_BYTES + W1T_BYTES + H1_BYTES + W2T_BYTES + B1P_BYTES);
  int* idx             = (int*)(ws + A_BYTES + W1T_BYTES + H1_BYTES + W2T_BYTES + B1P_BYTES + LG_BYTES);
  int* meta            = (int*)(ws + A_BYTES + W1T_BYTES + H1_BYTES + W2T_BYTES + B1P_BYTES + LG_BYTES + 66560);
  // transient compaction scratch lives inside h1 (h1 is written only later)
  int* upos            = (int*)h1c;                 // 64 KiB
  int* counts          = (int*)(h1c + 65536);       // 128 B
  int* offs            = (int*)(h1c + 65536 + 128); // 128 B

  hipFuncSetAttribute((const void*)gemm1_192_kernel,
                      hipFuncAttributeMaxDynamicSharedMemorySize, 114688);

  compact1_kernel<<<32, 512, 0, stream>>>(starts, upos, counts);
  compact2_kernel<<<1, 256, 0, stream>>>(counts, offs, meta, idx);
  compact3_kernel<<<32, 512, 0, stream>>>(starts, upos, offs, idx);
  prep_fused_kernel<<<4096, 256, 0, stream>>>(hs, idx, meta, W1, W2, b1,
                                              a, w1t, w2t, b1p);
  gemm1_192_kernel<<<352, 512, 114688, stream>>>(a, w1t, b1p, meta, h1);
  layer23_kernel<<<4096, 256, 0, stream>>>(h1, w2t, b2, W3, b3, idx, meta, logits);
  gather_kernel<<<64, 256, 0, stream>>>(starts, logits, out);
}

// Round 17
// 1017.975 us; speedup vs baseline: 1.0818x; 1.0207x over previous
//
#include <hip/hip_runtime.h>

typedef __attribute__((ext_vector_type(8))) short bf16x8;
typedef __attribute__((ext_vector_type(4))) float f32x4;

#define L_DIM 24
#define B_DIM 32
#define S_DIM 512
#define H_DIM 1024
#define M_DIM 16384      // B*S
#define K_DIM 24576      // L*H
#define N_REAL 900
#define NP 1024          // padded N
#define BM 192           // m-tile (0.75x blocks -> ~55 panels -> ~220 actives)

#define W1T_TILES 6144   // 16 x 384 tiles of 64x64
#define SMALL_CHUNKS 164

// round-to-nearest-even fp32 -> bf16
__device__ __forceinline__ short f2bf(float f) {
  unsigned u = __builtin_bit_cast(unsigned, f);
  u += 0x7FFFu + ((u >> 16) & 1u);
  return (short)(u >> 16);
}
__device__ __forceinline__ float bflo(unsigned u) { return __builtin_bit_cast(float, u << 16); }
__device__ __forceinline__ float bfhi(unsigned u) { return __builtin_bit_cast(float, u & 0xffff0000u); }

// ---- C1: per-batch flags + local prefix of unique nonzero starts (sorted input)
__global__ __launch_bounds__(512)
void compact1_kernel(const int* __restrict__ starts, int* __restrict__ upos,
                     int* __restrict__ counts) {
  __shared__ int sc[512];
  const int b = blockIdx.x, t = threadIdx.x;
  const int v = starts[b * 512 + t];
  const int prev = (t > 0) ? starts[b * 512 + t - 1] : -1;
  const int flag = (v != 0 && v != prev) ? 1 : 0;
  sc[t] = flag;
  __syncthreads();
#pragma unroll
  for (int off = 1; off < 512; off <<= 1) {
    const int x = (t >= off) ? sc[t - off] : 0;
    __syncthreads();
    sc[t] += x;
    __syncthreads();
  }
  upos[b * 512 + t] = flag ? (sc[t] - 1) : -1;
  if (t == 511) counts[b] = sc[511];
}

// ---- C2: scan counts -> offsets, Mc, Mc_pad (192-mult); pad idx tail with row 0
__global__ __launch_bounds__(256)
void compact2_kernel(const int* __restrict__ counts, int* __restrict__ offs,
                     int* __restrict__ meta, int* __restrict__ idx) {
  __shared__ int s0, s1;
  if (threadIdx.x == 0) {
    int acc = 0;
    for (int b = 0; b < 32; ++b) { offs[b] = acc; acc += counts[b]; }
    const int pad = ((acc + BM - 1) / BM) * BM;
    meta[0] = acc;                        // Mc
    meta[1] = pad;                        // Mc_pad (BM multiple)
    s0 = acc; s1 = pad;
  }
  __syncthreads();
  for (int j = s0 + threadIdx.x; j < s1; j += 256) idx[j] = 0;  // pad -> row 0
}

// ---- C3: scatter compact indices: idx[off_b + pos] = b*512 + value
__global__ __launch_bounds__(512)
void compact3_kernel(const int* __restrict__ starts, const int* __restrict__ upos,
                     const int* __restrict__ offs, int* __restrict__ idx) {
  const int b = blockIdx.x, t = threadIdx.x;
  const int p = upos[b * 512 + t];
  if (p >= 0) idx[offs[b] + p] = b * 512 + starts[b * 512 + t];
}

// =====================================================================
// P-fused: one kernel, three memory-bound work types co-resident so HBM
// stays saturated:
//   item < 6144              : one 64x64 W1->W1T transpose tile
//   item < 6144+Mc_pad       : one compacted-A row convert (fp32->bf16)
//   item < 6144+Mc_pad+164   : one prep_small chunk (W2T + b1p)
// =====================================================================
__global__ __launch_bounds__(256)
void prep_fused_kernel(const float* __restrict__ hs, const int* __restrict__ idx,
                       const int* __restrict__ meta,
                       const float* __restrict__ w1, const float* __restrict__ w2,
                       const float* __restrict__ b1,
                       unsigned short* __restrict__ a,
                       unsigned short* __restrict__ w1t,
                       float* __restrict__ w2t, float* __restrict__ b1p) {
  __shared__ unsigned short t[64][72];
  const int mcp = meta[1];
  const int total = W1T_TILES + mcp + SMALL_CHUNKS;
  const int tid = threadIdx.x;

  for (int item = blockIdx.x; item < total; item += gridDim.x) {
    if (item < W1T_TILES) {
      const int n0 = (item & 15) * 64;
      const int k0 = (item >> 4) * 64;
      {
        const int nl = tid & 63;
        const int n = n0 + nl;
#pragma unroll
        for (int p = 0; p < 16; ++p) {
          const int kl = p * 4 + (tid >> 6);
          float v = (n < N_REAL) ? w1[(size_t)(k0 + kl) * N_REAL + n] : 0.f;
          t[nl][kl] = (unsigned short)f2bf(v);
        }
      }
      __syncthreads();
      {
        const int kl = tid & 63;
#pragma unroll
        for (int p = 0; p < 16; ++p) {
          const int nl2 = p * 4 + (tid >> 6);
          const int n = n0 + nl2;
          const int slot = ((kl >> 3) ^ (n & 7)) & 7;
          w1t[(size_t)n * K_DIM + k0 + slot * 8 + (kl & 7)] = t[nl2][kl];
        }
      }
      __syncthreads();
    } else if (item < W1T_TILES + mcp) {
      const int j = item - W1T_TILES;
      const int m = idx[j];
      const int b = m >> 9, s = m & 511;
      const int j7 = j & 7;
      unsigned short* dstRow = a + (size_t)j * K_DIM;
#pragma unroll
      for (int i = 0; i < 12; ++i) {
        const int g = tid + i * 256;
        const int l = g >> 7;
        const int h = (g & 127) * 8;
        const float* src = hs + (((size_t)l * B_DIM + b) * S_DIM + s) * H_DIM + h;
        float4 f0 = *(const float4*)src;
        float4 f1 = *(const float4*)(src + 4);
        bf16x8 p;
        p[0] = f2bf(f0.x); p[1] = f2bf(f0.y); p[2] = f2bf(f0.z); p[3] = f2bf(f0.w);
        p[4] = f2bf(f1.x); p[5] = f2bf(f1.y); p[6] = f2bf(f1.z); p[7] = f2bf(f1.w);
        const int slot = (g & 7) ^ j7;
        *(bf16x8*)(dstRow + (g & ~7) * 8 + slot * 8) = p;
      }
    } else {
      const int i = (item - W1T_TILES - mcp) * 256 + tid;
      if (i < 40 * NP) {
        const int jj = i >> 10, k = i & (NP - 1);
        w2t[i] = (k < N_REAL) ? w2[(size_t)k * 40 + jj] : 0.f;
      }
      const int t2 = i - 40 * NP;
      if (t2 >= 0 && t2 < NP)
        b1p[t2] = (t2 < N_REAL) ? b1[t2] : 0.f;
    }
  }
}

// =====================================================================
// G1: h1(bf16) = relu(A @ W1T^T + b1). 192x256 tile, BK=64, 3-phase
// cadence with DEEP prefetch: A triple-buffered (staged 2 tiles ahead,
// ph1), Bb(t+1) at ph2, Ba(t+2) at ph3. Steady-state VMEM queue = 7
// outstanding [A(t+1)3, Bb(t)2, Ba(t+1)2]; drains: vmcnt(5) at ph1-end
// (lands A(t+1)+Bb(t), each >=2-3 phases in flight) and vmcnt(7) at
// ph3-end (lands Ba(t+1), 3 phases). Every stage gets >=1100cy of HBM
// flight time (was 550 worst-case for Bb). LDS 136 KiB, 1 block/CU.
// =====================================================================
#define SBAR() do { __builtin_amdgcn_sched_barrier(0); __builtin_amdgcn_s_barrier(); __builtin_amdgcn_sched_barrier(0); } while (0)
#define WAIT_LGKM0() do { asm volatile("s_waitcnt lgkmcnt(0)" ::: "memory"); __builtin_amdgcn_sched_barrier(0); } while (0)
#define VMWAIT(N) do { asm volatile("s_waitcnt vmcnt(" #N ")" ::: "memory"); __builtin_amdgcn_sched_barrier(0); } while (0)

// stage full 192-row A tile (24 KiB): 3 x global_load_lds per thread
#define STAGE_A(DSTREG, TK) do {                                                       \
  _Pragma("unroll")                                                                    \
  for (int _i = 0; _i < 3; ++_i) {                                                     \
    const int _ch = wid * 3 + _i;                                                      \
    const int _row = _ch * 8 + (lane >> 3);                                            \
    __builtin_amdgcn_global_load_lds(                                                  \
      (const __attribute__((address_space(1))) void*)(a +                              \
          (size_t)(m0 + _row) * K_DIM + (TK) * 64 + (lane & 7) * 8),                   \
      (__attribute__((address_space(3))) void*)((DSTREG) + _ch * 1024),                \
      16, 0, 0);                                                                       \
  }                                                                                    \
} while (0)

// stage one 128-row half of B tile (16 KiB): 2 x global_load_lds per thread
#define STAGE_B(DSTREG, HALF, TK) do {                                                 \
  _Pragma("unroll")                                                                    \
  for (int _i = 0; _i < 2; ++_i) {                                                     \
    const int _ch = wid * 2 + _i;                                                      \
    const int _row = (HALF) * 128 + _ch * 8 + (lane >> 3);                             \
    __builtin_amdgcn_global_load_lds(                                                  \
      (const __attribute__((address_space(1))) void*)(w1t +                            \
          (size_t)(n0 + _row) * K_DIM + (TK) * 64 + (lane & 7) * 8),                   \
      (__attribute__((address_space(3))) void*)((DSTREG) + (HALF) * 16384 + _ch * 1024), \
      16, 0, 0);                                                                       \
  }                                                                                    \
} while (0)

// A fragments: half h = MIBASE/3; rows h*96 + wr*48 + {0,16,32} + r15, both kk
#define LDA3(AV, MIBASE, ABUF) do {                                                    \
  _Pragma("unroll")                                                                    \
  for (int _mi = 0; _mi < 3; ++_mi) {                                                  \
    _Pragma("unroll")                                                                  \
    for (int _kk = 0; _kk < 2; ++_kk) {                                                \
      const int _r = ((MIBASE) / 3) * 96 + wr * 48 + _mi * 16 + r15;                   \
      AV[_mi][_kk] = *(const bf16x8*)((ABUF) + _r * 128 + (((_kk)*4 + hi4) ^ (_r & 7)) * 16); \
    }                                                                                  \
  }                                                                                    \
} while (0)

// B fragments: half = NIBASE>>1; rows half*128 + wc*32 + {0,16} + r15, both kk
#define LDB2(BV, NIBASE, BBUF) do {                                                    \
  _Pragma("unroll")                                                                    \
  for (int _ni = 0; _ni < 2; ++_ni) {                                                  \
    _Pragma("unroll")                                                                  \
    for (int _kk = 0; _kk < 2; ++_kk) {                                                \
      const int _r = ((NIBASE) >> 1) * 128 + wc * 32 + _ni * 16 + r15;                 \
      BV[_ni][_kk] = *(const bf16x8*)((BBUF) + _r * 128 + (((_kk)*4 + hi4) ^ (_r & 7)) * 16); \
    }                                                                                  \
  }                                                                                    \
} while (0)

#define MFMA_Q(AV, BV, MIBASE, NIBASE) do {                                            \
  _Pragma("unroll")                                                                    \
  for (int _mi = 0; _mi < 3; ++_mi)                                                    \
    _Pragma("unroll")                                                                  \
    for (int _ni = 0; _ni < 2; ++_ni)                                                  \
      _Pragma("unroll")                                                                \
      for (int _kk = 0; _kk < 2; ++_kk)                                                \
        acc[(MIBASE) + _mi][(NIBASE) + _ni] = __builtin_amdgcn_mfma_f32_16x16x32_bf16( \
            AV[_mi][_kk], BV[_ni][_kk], acc[(MIBASE) + _mi][(NIBASE) + _ni], 0, 0, 0); \
} while (0)

// one K-tile = 3 phases. SA: stage A(t+2) into A2B (ph1); SBB: Bb(t+1)
// into BBN (ph2); SBA: Ba(t+2) into BB current (ph3).
// Write-after-read: A(t+2) slot == A(t-1) slot, last read t-1 ph3 -> write
// t ph1 (1 barrier). Bb(t+1) buf == B(t-1) buf, Bb half last read t-1 ph2.
// Ba(t+2) buf == B(t) buf, Ba half last read t ph1 -> write ph3.
#define TILE_BODY(T, AB, BB, A2B, BBN, SA, SBB, SBA, W1STMT, W3STMT) do {              \
  /* ---- phase 1: Aa x Ba ---- */                                                     \
  LDA3(av, 0, (AB));                                                                   \
  LDB2(bv0, 0, (BB));                                                                  \
  if (SA) STAGE_A((A2B), (T) + 2);                                                     \
  SBAR();                                                                              \
  WAIT_LGKM0();                                                                        \
  __builtin_amdgcn_s_setprio(1);                                                       \
  MFMA_Q(av, bv0, 0, 0);                                                               \
  __builtin_amdgcn_s_setprio(0);                                                       \
  W1STMT;                                                                              \
  SBAR();                                                                              \
  /* ---- phase 2: Aa x Bb ---- */                                                     \
  LDB2(bv1, 2, (BB));                                                                  \
  if (SBB) STAGE_B((BBN), 1, (T) + 1);                                                 \
  SBAR();                                                                              \
  WAIT_LGKM0();                                                                        \
  __builtin_amdgcn_s_setprio(1);                                                       \
  MFMA_Q(av, bv1, 0, 2);                                                               \
  __builtin_amdgcn_s_setprio(0);                                                       \
  SBAR();                                                                              \
  /* ---- phase 3: Ab x (Bb, Ba) ---- */                                               \
  LDA3(av, 3, (AB));                                                                   \
  if (SBA) STAGE_B((BB), 0, (T) + 2);                                                  \
  SBAR();                                                                              \
  WAIT_LGKM0();                                                                        \
  __builtin_amdgcn_s_setprio(1);                                                       \
  MFMA_Q(av, bv1, 3, 2);                                                               \
  MFMA_Q(av, bv0, 3, 0);                                                               \
  __builtin_amdgcn_s_setprio(0);                                                       \
  W3STMT;                                                                              \
  SBAR();                                                                              \
} while (0)

__global__ __launch_bounds__(512, 2)
void gemm1_192_kernel(const unsigned short* __restrict__ a,
                      const unsigned short* __restrict__ w1t,
                      const float* __restrict__ b1p,
                      const int* __restrict__ meta,
                      unsigned short* __restrict__ h1) {
  const int n_panels = meta[1] / BM;

  // XCD mapping: panel mb's 4 n-blocks share XCD c = mb&7
  const int hw = blockIdx.x;
  const int c = hw & 7;
  const int r = hw >> 3;              // 0..43
  const int mb = (r >> 2) * 8 + c;
  if (mb >= n_panels) return;
  const int nb = r & 3;
  const int m0 = mb * BM;
  const int n0 = nb * 256;

  extern __shared__ char L[];   // 136 KiB: A0|A1|A2 (24K each) | B0|B1 (32K each)
  char* const Ab0 = L;
  char* const Ab1 = L + 24576;
  char* const Ab2 = L + 49152;
  char* const Bq0 = L + 73728;
  char* const Bq1 = L + 106496;

  const int tid = threadIdx.x;
  const int lane = tid & 63;
  const int wid = tid >> 6;          // 0..7
  const int wr = wid >> 2;           // 0..1 (48-row band within each 96-half)
  const int wc = wid & 3;            // 0..3 (32-col band within each 128-half)
  const int r15 = lane & 15;
  const int hi4 = lane >> 4;         // 0..3

  f32x4 acc[6][4] = {};
  bf16x8 av[3][2], bv0[2][2], bv1[2][2];

  // prologue, issue order: A(0)3, Ba(0)2 | A(1)3, Bb(0)2, Ba(1)2
  STAGE_A(Ab0, 0);
  STAGE_B(Bq0, 0, 0);
  STAGE_A(Ab1, 1);
  STAGE_B(Bq0, 1, 0);
  STAGE_B(Bq1, 0, 1);
  VMWAIT(7);      // land A(0), Ba(0); leave [A(1)3, Bb(0)2, Ba(1)2] in flight
  SBAR();

  // main loop: tiles 0..377, 6-tile unroll for the %3 / %2 buffer cycle
  for (int kt = 0; kt < 63; ++kt) {
    const int t = 6 * kt;
    TILE_BODY(t + 0, Ab0, Bq0, Ab2, Bq1, 1, 1, 1, VMWAIT(5), VMWAIT(7));
    TILE_BODY(t + 1, Ab1, Bq1, Ab0, Bq0, 1, 1, 1, VMWAIT(5), VMWAIT(7));
    TILE_BODY(t + 2, Ab2, Bq0, Ab1, Bq1, 1, 1, 1, VMWAIT(5), VMWAIT(7));
    TILE_BODY(t + 3, Ab0, Bq1, Ab2, Bq0, 1, 1, 1, VMWAIT(5), VMWAIT(7));
    TILE_BODY(t + 4, Ab1, Bq0, Ab0, Bq1, 1, 1, 1, VMWAIT(5), VMWAIT(7));
    TILE_BODY(t + 5, Ab2, Bq1, Ab1, Bq0, 1, 1, 1, VMWAIT(5), VMWAIT(7));
  }
  // tail: 378-381 steady (last valid stages: A(383)@381, Bb(382)@381, Ba(383)@381)
  TILE_BODY(378, Ab0, Bq0, Ab2, Bq1, 1, 1, 1, VMWAIT(5), VMWAIT(7));
  TILE_BODY(379, Ab1, Bq1, Ab0, Bq0, 1, 1, 1, VMWAIT(5), VMWAIT(7));
  TILE_BODY(380, Ab2, Bq0, Ab1, Bq1, 1, 1, 1, VMWAIT(5), VMWAIT(7));
  TILE_BODY(381, Ab0, Bq1, Ab2, Bq0, 1, 1, 1, VMWAIT(5), VMWAIT(7));
  // 382: only Bb(383); queue [A(383)3,Bb(382)2,Ba(383)2] -> vmcnt(2) lands
  // A(383)+Bb(382); ph3 vmcnt(2) lands Ba(383), leaves Bb(383)2.
  TILE_BODY(382, Ab1, Bq0, Ab2, Bq1, 0, 1, 0, VMWAIT(2), VMWAIT(2));
  // 383: compute only; vmcnt(0) lands Bb(383) before its ph2 reads.
  TILE_BODY(383, Ab2, Bq1, Ab0, Bq0, 0, 0, 0, VMWAIT(0), (void)0);

  // epilogue: relu(acc + b1) -> bf16; C/D: col = lane&15, row = (lane>>4)*4 + rr
#pragma unroll
  for (int mi = 0; mi < 6; ++mi) {
#pragma unroll
    for (int ni = 0; ni < 4; ++ni) {
      const int n = n0 + (ni >> 1) * 128 + wc * 32 + (ni & 1) * 16 + r15;
      const float bias = b1p[n];
#pragma unroll
      for (int rr = 0; rr < 4; ++rr) {
        const int m = m0 + (mi / 3) * 96 + wr * 48 + (mi % 3) * 16 + hi4 * 4 + rr;
        const float v = acc[mi][ni][rr] + bias;
        h1[(size_t)m * NP + n] = (unsigned short)f2bf(v > 0.f ? v : 0.f);
      }
    }
  }
}

// ---- K2: logits = sigmoid(relu(h1 @ W2 + b2) @ W3 + b3), one wave per
//          COMPACT row j (h1 in bf16); writes at original position idx[j].
__global__ __launch_bounds__(256)
void layer23_kernel(const unsigned short* __restrict__ h1, const float* __restrict__ w2t,
                    const float* __restrict__ b2, const float* __restrict__ w3,
                    const float* __restrict__ b3, const int* __restrict__ idx,
                    const int* __restrict__ meta, float* __restrict__ logits) {
  const int j = (blockIdx.x * 256 + threadIdx.x) >> 6;
  if (j >= meta[0]) return;
  const int lane = threadIdx.x & 63;
  const unsigned short* hrow = h1 + (size_t)j * NP;
  float acc = 0.f;
  if (lane < 40) {
    const float* wrow = w2t + lane * NP;
    for (int k = 0; k < NP; k += 8) {
      uint4 q = *(const uint4*)(hrow + k);
      float4 w0 = *(const float4*)(wrow + k);
      float4 w4 = *(const float4*)(wrow + k + 4);
      acc += bflo(q.x) * w0.x + bfhi(q.x) * w0.y;
      acc += bflo(q.y) * w0.z + bfhi(q.y) * w0.w;
      acc += bflo(q.z) * w4.x + bfhi(q.z) * w4.y;
      acc += bflo(q.w) * w4.z + bfhi(q.w) * w4.w;
    }
    acc += b2[lane];
    acc = acc > 0.f ? acc : 0.f;
    acc *= w3[lane];
  }
#pragma unroll
  for (int off = 32; off > 0; off >>= 1)
    acc += __shfl_down(acc, off);
  if (lane == 0)
    logits[idx[j]] = 1.f / (1.f + expf(-(acc + b3[0])));
}

// ---- K3: ragged gather
__global__ __launch_bounds__(256)
void gather_kernel(const int* __restrict__ starts, const float* __restrict__ logits,
                   float* __restrict__ out) {
  const int i = blockIdx.x * 256 + threadIdx.x;
  if (i >= M_DIM) return;
  const int st = starts[i];
  int idx = st;
  if (idx < 0) idx = 0;
  if (idx > S_DIM - 1) idx = S_DIM - 1;
  out[i] = (st != 0) ? logits[((i >> 9) << 9) + idx] : 0.f;
}

extern "C" void kernel_launch(void* const* d_in, const int* in_sizes, int n_in,
                              void* d_out, int out_size, void* d_ws, size_t ws_size,
                              hipStream_t stream) {
  const float* hs = (const float*)d_in[0];
  const float* W1 = (const float*)d_in[1];
  const float* b1 = (const float*)d_in[2];
  const float* W2 = (const float*)d_in[3];
  const float* b2 = (const float*)d_in[4];
  const float* W3 = (const float*)d_in[5];
  const float* b3 = (const float*)d_in[6];
  const int* starts = (const int*)d_in[7];
  float* out = (float*)d_out;
  char* ws = (char*)d_ws;

  const size_t A_BYTES   = (size_t)(M_DIM + 256) * K_DIM * 2;  // slack for 192-pad
  const size_t W1T_BYTES = (size_t)NP * K_DIM * 2;             //    50,331,648
  const size_t H1_BYTES  = (size_t)(M_DIM + 256) * NP * 2;     // bf16 h1
  const size_t W2T_BYTES = 40 * NP * 4;
  const size_t B1P_BYTES = NP * 4;
  const size_t LG_BYTES  = M_DIM * 4;

  unsigned short* a    = (unsigned short*)ws;
  unsigned short* w1t  = (unsigned short*)(ws + A_BYTES);
  char* h1c            = ws + A_BYTES + W1T_BYTES;
  unsigned short* h1   = (unsigned short*)h1c;
  float* w2t           = (float*)(ws + A_BYTES + W1T_BYTES + H1_BYTES);
  float* b1p           = (float*)(ws + A_BYTES + W1T_BYTES + H1_BYTES + W2T_BYTES);
  float* logits        = (float*)(ws + A_BYTES + W1T_BYTES + H1_BYTES + W2T_BYTES + B1P_BYTES);
  int* idx             = (int*)(ws + A_BYTES + W1T_BYTES + H1_BYTES + W2T_BYTES + B1P_BYTES + LG_BYTES);
  int* meta            = (int*)(ws + A_BYTES + W1T_BYTES + H1_BYTES + W2T_BYTES + B1P_BYTES + LG_BYTES + 66560);
  // transient compaction scratch lives inside h1 (h1 is written only later)
  int* upos            = (int*)h1c;                 // 64 KiB
  int* counts          = (int*)(h1c + 65536);       // 128 B
  int* offs            = (int*)(h1c + 65536 + 128); // 128 B

  hipFuncSetAttribute((const void*)gemm1_192_kernel,
                      hipFuncAttributeMaxDynamicSharedMemorySize, 139264);

  compact1_kernel<<<32, 512, 0, stream>>>(starts, upos, counts);
  compact2_kernel<<<1, 256, 0, stream>>>(counts, offs, meta, idx);
  compact3_kernel<<<32, 512, 0, stream>>>(starts, upos, offs, idx);
  prep_fused_kernel<<<4096, 256, 0, stream>>>(hs, idx, meta, W1, W2, b1,
                                              a, w1t, w2t, b1p);
  gemm1_192_kernel<<<352, 512, 139264, stream>>>(a, w1t, b1p, meta, h1);
  layer23_kernel<<<4096, 256, 0, stream>>>(h1, w2t, b2, W3, b3, idx, meta, logits);
  gather_kernel<<<64, 256, 0, stream>>>(starts, logits, out);
}